// Round 1
// baseline (1506.218 us; speedup 1.0000x reference)
//
#include <hip/hip_runtime.h>
#include <stdint.h>
#include <stddef.h>

// CharPredictorMultirateFFN on MI355X (gfx950).
// Pipeline: gather(+pad) -> conv_w transpose -> lin_w transpose -> conv GEMM (fp16 MFMA)
//           -> linear GEMM + fused softmax.
// Conv trick: with kk = k*E + e, im2col A is contiguous rows of the padded emb buffer
// (15 zero rows per batch item), so the conv is a plain GEMM M=65536,N=1024,K=8192.

typedef _Float16 f16;
typedef __attribute__((ext_vector_type(8))) _Float16 f16x8;
typedef __attribute__((ext_vector_type(4))) float f32x4;

#define SP 2063  // padded rows per batch item: 15 + 2048

__device__ __forceinline__ void gl2lds16(const void* g, void* l) {
  __builtin_amdgcn_global_load_lds((const __attribute__((address_space(1))) void*)g,
                                   (__attribute__((address_space(3))) void*)l, 16, 0, 0);
}

// ---------------- gather: emb_table[seq] -> f16 padded buffer [32][2063][512] --------
__global__ __launch_bounds__(256) void k_gather(const int* __restrict__ seq,
                                                const float* __restrict__ tab,
                                                f16* __restrict__ embp) {
  int row = blockIdx.x * 4 + (threadIdx.x >> 6);   // 0 .. 66015
  int lane = threadIdx.x & 63;
  int b = row / SP;
  int r = row - b * SP;
  f16* dst = embp + (size_t)row * 512 + lane * 8;
  if (r < 15) {
    f16x8 z = {(f16)0, (f16)0, (f16)0, (f16)0, (f16)0, (f16)0, (f16)0, (f16)0};
    *(f16x8*)dst = z;
  } else {
    int idx = seq[b * 2048 + (r - 15)];
    const float4* src = (const float4*)(tab + (size_t)idx * 512 + lane * 8);
    float4 v0 = src[0], v1 = src[1];
    f16x8 o;
    o[0] = (f16)v0.x; o[1] = (f16)v0.y; o[2] = (f16)v0.z; o[3] = (f16)v0.w;
    o[4] = (f16)v1.x; o[5] = (f16)v1.y; o[6] = (f16)v1.z; o[7] = (f16)v1.w;
    *(f16x8*)dst = o;
  }
}

// ---------------- conv_w [H][E][K] f32 -> wt2 [256 kblk][1024 h][32] f16 -------------
// kk = k*512 + e ; kblk = kk>>5 = k*16 + (e>>5) ; inner = e&31
__global__ __launch_bounds__(256) void k_twc(const float* __restrict__ cw,
                                             f16* __restrict__ wt2) {
  int o = blockIdx.x * 256 + threadIdx.x;  // 8388608 outputs
  int e5 = o & 31;
  int h = (o >> 5) & 1023;
  int kb = o >> 15;            // 0..255
  int k = kb >> 4;
  int e = ((kb & 15) << 5) | e5;
  wt2[o] = (f16)cw[(size_t)h * 8192 + e * 16 + k];
}

// ---------------- lin_w [V][F] f32 -> lt2 [48 fblk][256 v][32] f16 -------------------
__global__ __launch_bounds__(256) void k_twl(const float* __restrict__ lw,
                                             f16* __restrict__ lt2) {
  int o = blockIdx.x * 256 + threadIdx.x;  // 393216 outputs
  int f5 = o & 31;
  int v = (o >> 5) & 255;
  int kb = o >> 13;            // 0..47
  int f = (kb << 5) | f5;
  lt2[o] = (f16)lw[(size_t)v * 1536 + f];
}

// ---------------- conv GEMM: [65536 x 8192] x [8192 x 1024] -> relu -> f16 -----------
__global__ __launch_bounds__(256) void k_conv(const f16* __restrict__ embp,
                                              const f16* __restrict__ wt2,
                                              const float* __restrict__ cb,
                                              f16* __restrict__ cout) {
  __shared__ __align__(16) f16 As[128 * 32];
  __shared__ __align__(16) f16 Bs[128 * 32];
  int m0 = blockIdx.x << 7;           // 0..65408
  int n0 = blockIdx.y << 7;           // 0..896
  int b = m0 >> 11, t0 = m0 & 2047;
  int tid = threadIdx.x, lane = tid & 63, wave = tid >> 6;
  int sr = lane >> 2;                 // row within 16-row chunk
  int sc = (lane & 3) << 3;           // halves within 32-half row
  // A rows are contiguous padded-emb rows: A[m][kk] = embp[(b*SP + t)*512 + kk]
  const f16* gA0 = embp + (size_t)(b * SP + t0 + wave * 16 + sr) * 512 + sc;
  const f16* gA1 = embp + (size_t)(b * SP + t0 + (4 + wave) * 16 + sr) * 512 + sc;
  const f16* gB0 = wt2 + (size_t)(n0 + wave * 16 + sr) * 32 + sc;
  const f16* gB1 = wt2 + (size_t)(n0 + (4 + wave) * 16 + sr) * 32 + sc;
  f16* lA0 = As + wave * 512;
  f16* lA1 = As + (4 + wave) * 512;
  f16* lB0 = Bs + wave * 512;
  f16* lB1 = Bs + (4 + wave) * 512;
  int wr = wave >> 1, wc = wave & 1;
  int fr = lane & 15, fq = (lane >> 4) << 3;
  f32x4 zero = {0.f, 0.f, 0.f, 0.f};
  f32x4 acc[4][4];
#pragma unroll
  for (int i = 0; i < 4; ++i)
#pragma unroll
    for (int j = 0; j < 4; ++j) acc[i][j] = zero;

  for (int kb = 0; kb < 256; ++kb) {
    gl2lds16(gA0, lA0);
    gl2lds16(gA1, lA1);
    gl2lds16(gB0, lB0);
    gl2lds16(gB1, lB1);
    __syncthreads();
    f16x8 af[4], bf[4];
#pragma unroll
    for (int i = 0; i < 4; ++i)
      af[i] = *(const f16x8*)(As + (wr * 64 + i * 16 + fr) * 32 + fq);
#pragma unroll
    for (int j = 0; j < 4; ++j)
      bf[j] = *(const f16x8*)(Bs + (wc * 64 + j * 16 + fr) * 32 + fq);
#pragma unroll
    for (int i = 0; i < 4; ++i)
#pragma unroll
      for (int j = 0; j < 4; ++j)
        acc[i][j] = __builtin_amdgcn_mfma_f32_16x16x32_f16(af[i], bf[j], acc[i][j], 0, 0, 0);
    __syncthreads();
    gA0 += 32; gA1 += 32;
    gB0 += 32768; gB1 += 32768;   // next 32x1024 weight block
  }
  // epilogue: bias + relu + f16 store. C/D: col=lane&15 (n), row=(lane>>4)*4+reg (m)
  int col = lane & 15, rq = (lane >> 4) << 2;
  int mbase = m0 + wr * 64 + rq;
  int nbase = n0 + wc * 64 + col;
#pragma unroll
  for (int j = 0; j < 4; ++j) {
    int h = nbase + j * 16;
    float bias = cb[h];
#pragma unroll
    for (int i = 0; i < 4; ++i) {
      int m = mbase + i * 16;
#pragma unroll
      for (int rg = 0; rg < 4; ++rg) {
        float v = acc[i][j][rg] + bias;
        v = v > 0.f ? v : 0.f;
        cout[(size_t)(m + rg) * 1024 + h] = (f16)v;
      }
    }
  }
}

// ---------------- linear GEMM [65536 x 1536] x [1536 x 256] + fused softmax ----------
__global__ __launch_bounds__(256) void k_lin(const f16* __restrict__ embp,
                                             const f16* __restrict__ cout,
                                             const f16* __restrict__ lt2,
                                             const float* __restrict__ lb,
                                             float* __restrict__ out) {
  __shared__ __align__(16) char smem[32 * 261 * 4];  // Ls overlays As|Bs
  __shared__ float pmax[4][32], psum[4][32], mrow[32], rinv[32];
  f16* As = (f16*)smem;             // [64][32]   4 KB
  f16* Bs = (f16*)(smem + 4096);    // [256][32] 16 KB
  float* Ls = (float*)smem;         // [32][261] f32 epilogue logits
  int m0 = blockIdx.x << 6;
  int b = m0 >> 11, t0 = m0 & 2047;
  int tid = threadIdx.x, lane = tid & 63, wave = tid >> 6;
  int sr = lane >> 2, sc = (lane & 3) << 3;
  const f16* gAe = embp + (size_t)(b * SP + 15 + t0 + wave * 16 + sr) * 512 + sc;
  const f16* gAc = cout + (size_t)(m0 + wave * 16 + sr) * 1024 + sc;
  f16* lA = As + wave * 512;
  int fr = lane & 15, fq = (lane >> 4) << 3;
  f32x4 zero = {0.f, 0.f, 0.f, 0.f};
  f32x4 acc[4][4];
#pragma unroll
  for (int i = 0; i < 4; ++i)
#pragma unroll
    for (int j = 0; j < 4; ++j) acc[i][j] = zero;

  for (int kb = 0; kb < 48; ++kb) {
    if (kb < 16) gl2lds16(gAe + kb * 32, lA);
    else         gl2lds16(gAc + (kb - 16) * 32, lA);
#pragma unroll
    for (int jj = 0; jj < 4; ++jj) {
      int c = wave * 4 + jj;
      gl2lds16(lt2 + (size_t)kb * 8192 + (c * 16 + sr) * 32 + sc, Bs + c * 512);
    }
    __syncthreads();
    f16x8 af[4], bf[4];
#pragma unroll
    for (int i = 0; i < 4; ++i)
      af[i] = *(const f16x8*)(As + (i * 16 + fr) * 32 + fq);
#pragma unroll
    for (int j = 0; j < 4; ++j)
      bf[j] = *(const f16x8*)(Bs + (wave * 64 + j * 16 + fr) * 32 + fq);
#pragma unroll
    for (int i = 0; i < 4; ++i)
#pragma unroll
      for (int j = 0; j < 4; ++j)
        acc[i][j] = __builtin_amdgcn_mfma_f32_16x16x32_f16(af[i], bf[j], acc[i][j], 0, 0, 0);
    __syncthreads();
  }

  // softmax epilogue, two 32-row halves (keeps LDS small). Ls stride 261 avoids
  // 8-way bank conflicts on the per-row column scans (261%32=5, coprime with 32).
  int col = lane & 15, rq = (lane >> 4) << 2;
  for (int hf = 0; hf < 2; ++hf) {
    __syncthreads();
#pragma unroll
    for (int j = 0; j < 4; ++j) {
      int v = wave * 64 + j * 16 + col;
      float bias = lb[v];
#pragma unroll
      for (int i = 0; i < 2; ++i) {
        int rloc = i * 16 + rq;
        int ig = hf * 2 + i;
#pragma unroll
        for (int rg = 0; rg < 4; ++rg)
          Ls[(rloc + rg) * 261 + v] = acc[ig][j][rg] + bias;
      }
    }
    __syncthreads();
    if (tid < 128) {
      int r = tid & 31, q = tid >> 5;
      const float* rowp = Ls + r * 261 + q * 64;
      float pm = -1e30f;
#pragma unroll 8
      for (int c = 0; c < 64; ++c) pm = fmaxf(pm, rowp[c]);
      pmax[q][r] = pm;
    }
    __syncthreads();
    if (tid < 32)
      mrow[tid] = fmaxf(fmaxf(pmax[0][tid], pmax[1][tid]), fmaxf(pmax[2][tid], pmax[3][tid]));
    __syncthreads();
    if (tid < 128) {
      int r = tid & 31, q = tid >> 5;
      const float* rowp = Ls + r * 261 + q * 64;
      float mr = mrow[r], ps = 0.f;
#pragma unroll 8
      for (int c = 0; c < 64; ++c) ps += __expf(rowp[c] - mr);
      psum[q][r] = ps;
    }
    __syncthreads();
    if (tid < 32)
      rinv[tid] = 1.f / (psum[0][tid] + psum[1][tid] + psum[2][tid] + psum[3][tid]);
    __syncthreads();
    float* obase = out + (size_t)(m0 + hf * 32) * 256 + tid;
#pragma unroll 4
    for (int r = 0; r < 32; ++r)
      obase[(size_t)r * 256] = __expf(Ls[r * 261 + tid] - mrow[r]) * rinv[r];
  }
}

extern "C" void kernel_launch(void* const* d_in, const int* in_sizes, int n_in,
                              void* d_out, int out_size, void* d_ws, size_t ws_size,
                              hipStream_t stream) {
  const int*   seq = (const int*)d_in[0];
  const float* tab = (const float*)d_in[1];
  const float* cw  = (const float*)d_in[2];
  const float* cb  = (const float*)d_in[3];
  const float* lw  = (const float*)d_in[4];
  const float* lb  = (const float*)d_in[5];
  float* out = (float*)d_out;
  char* ws = (char*)d_ws;
  // workspace layout (needs ~219.4 MB):
  f16* embp = (f16*)(ws);               //  67,600,384 B  [32*2063][512]
  f16* cout = (f16*)(ws + 67600384);    // 134,217,728 B  [65536][1024]
  f16* wt2  = (f16*)(ws + 201818112);   //  16,777,216 B  [256][1024][32]
  f16* lt2  = (f16*)(ws + 218595328);   //     786,432 B  [48][256][32]

  hipLaunchKernelGGL(k_gather, dim3(16504), dim3(256), 0, stream, seq, tab, embp);
  hipLaunchKernelGGL(k_twc,    dim3(32768), dim3(256), 0, stream, cw, wt2);
  hipLaunchKernelGGL(k_twl,    dim3(1536),  dim3(256), 0, stream, lw, lt2);
  hipLaunchKernelGGL(k_conv,   dim3(512, 8), dim3(256), 0, stream, embp, wt2, cb, cout);
  hipLaunchKernelGGL(k_lin,    dim3(1024),  dim3(256), 0, stream, embp, cout, lt2, lb, out);
}